// Round 1
// 218.454 us; speedup vs baseline: 1.0269x; 1.0269x over previous
//
#include <hip/hip_runtime.h>
#include <stdint.h>

typedef __bf16 bf16x8 __attribute__((ext_vector_type(8)));
typedef float  f32x4  __attribute__((ext_vector_type(4)));

#define NB   32
#define CI   128
#define HH   56
#define WW   56
#define CO   256
#define HP   58          // 56 + 2 halo
#define HW   (HH*WW)     // 3136
#define MTOT (NB*HW)     // 100352
#define KTOT 1152        // 9*128, k = (r*3+s)*128 + c

#define XT_ELEMS ((size_t)NB*HP*HP*CI)   // 13,778,944
#define XT_BYTES (XT_ELEMS*2)            // 27,557,888 (16B-aligned)

// ---------- zero only the halo ring of padded x_t ----------
__global__ void halo_zero(__bf16* __restrict__ xt) {
  int id = blockIdx.x * 256 + threadIdx.x;
  if (id >= NB * 228 * 16) return;
  int chunk = id & 15;
  int p = (id >> 4) % 228;
  int n = id / (228 * 16);
  int h, w;
  if (p < 58)       { h = 0;           w = p; }
  else if (p < 116) { h = 57;          w = p - 58; }
  else if (p < 172) { h = p - 116 + 1; w = 0; }
  else              { h = p - 172 + 1; w = 57; }
  int4* dst = (int4*)(xt + ((size_t)(n * HP + h) * HP + w) * CI) + chunk;
  *dst = make_int4(0, 0, 0, 0);
}

// ---------- x: NCHW f32 -> padded NHWC bf16 (LDS transpose per (n,h)) ----------
__global__ void xpose_kernel(const float* __restrict__ x, __bf16* __restrict__ xt) {
  int nh = blockIdx.x;
  int n = nh / HH, h = nh % HH;
  __shared__ float tile[CI][57];
  const float* src = x + (size_t)n * CI * HW + (size_t)h * WW;
  int t = threadIdx.x;
  for (int idx = t; idx < CI * 14; idx += 256) {
    int c = idx / 14, w4 = idx - c * 14;
    float4 v = *(const float4*)(src + (size_t)c * HW + w4 * 4);
    tile[c][w4 * 4 + 0] = v.x;
    tile[c][w4 * 4 + 1] = v.y;
    tile[c][w4 * 4 + 2] = v.z;
    tile[c][w4 * 4 + 3] = v.w;
  }
  __syncthreads();
  __bf16* dst = xt + ((size_t)(n * HP + h + 1) * HP + 1) * CI;
  for (int idx = t; idx < WW * 16; idx += 256) {
    int w = idx >> 4, c8 = (idx & 15) * 8;
    bf16x8 v;
    for (int k = 0; k < 8; ++k) v[k] = (__bf16)tile[c8 + k][w];
    *(bf16x8*)(dst + (size_t)w * CI + c8) = v;
  }
}

// ---------- weight: OIHW f32 -> [CO][KTOT] bf16, k=(r*3+s)*128+c ----------
__global__ void wxform_kernel(const float* __restrict__ wg, __bf16* __restrict__ wt) {
  int id = blockIdx.x * 256 + threadIdx.x;   // CO*KTOT = 294912 total
  int o = id / KTOT;
  int k = id - o * KTOT;
  int rs = k >> 7, c = k & 127;
  wt[id] = (__bf16)wg[(size_t)o * KTOT + c * 9 + rs];
}

// ---------- implicit-GEMM conv: 3-buffer deep pipeline (T2+T3+T4+T5) ----------
// BM=128 (all 256 out-ch per block => A fetched once, B L2-resident).
// BK=64: LDS rows are 128 B, XOR-swizzled via pre-swizzled GLOBAL source so the
// global_load_lds dest stays linear (m201 stage/read pair).
// 3 LDS buffers (A 3x16KB @0, B 3x32KB @49152 = 144 KB): compute kt from
// buf[kt%3] while staging kt+2 into buf[(kt+2)%3]; ONE raw s_barrier per K-tile
// with s_waitcnt vmcnt(6) (6 = this tile's in-flight issues) - never drains to 0.
#define BM 128
#define BN 256
#define NKT 18   // KTOT/64

#define STAGE_A2(BS, OFF) \
  { _Pragma("unroll") for (int i_ = 0; i_ < 2; ++i_) \
      __builtin_amdgcn_global_load_lds( \
        (const __attribute__((address_space(1))) void*)(xtc + baseA[i_] + (OFF)), \
        (__attribute__((address_space(3))) void*)(lds + (BS)*16384 + i_*8192 + ldst), 16, 0, 0); }

#define STAGE_B01(BS, OFF) \
  { _Pragma("unroll") for (int i_ = 0; i_ < 2; ++i_) \
      __builtin_amdgcn_global_load_lds( \
        (const __attribute__((address_space(1))) void*)(wtc + baseB[i_] + (OFF)), \
        (__attribute__((address_space(3))) void*)(lds + 49152 + (BS)*32768 + i_*8192 + ldst), 16, 0, 0); }

#define STAGE_B23(BS, OFF) \
  { _Pragma("unroll") for (int i_ = 2; i_ < 4; ++i_) \
      __builtin_amdgcn_global_load_lds( \
        (const __attribute__((address_space(1))) void*)(wtc + baseB[i_] + (OFF)), \
        (__attribute__((address_space(3))) void*)(lds + 49152 + (BS)*32768 + i_*8192 + ldst), 16, 0, 0); }

// One K-tile: reads (swizzled) -> stage A+B01 -> MFMA b0,1 -> read B hi ->
// stage B23 -> MFMA b2,3 -> vmcnt(N) -> s_barrier. DOSTAGE/DOBAR fold at compile time.
#define KBODY(KT, BC, BS, DOSTAGE, DOBAR, VMCLIT) do { \
  int kt2_ = (KT) + 2; \
  int rs2_ = kt2_ >> 1; int r2_ = (rs2_*11)>>5; int s2_ = rs2_ - 3*r2_; \
  uint32_t offA2_ = (uint32_t)((r2_*HP + s2_) * 256 + (kt2_ & 1) * 128); \
  uint32_t offB2_ = (uint32_t)(kt2_ * 128); \
  const char* Ab_ = lds + (BC)*16384; \
  const char* Bb_ = lds + 49152 + (BC)*32768; \
  bf16x8 av_[4][2], bva_[2][2], bvb_[2][2]; \
  _Pragma("unroll") for (int a_ = 0; a_ < 4; ++a_) { \
    av_[a_][0] = *(const bf16x8*)(Ab_ + rowA + a_*2048 + slot0); \
    av_[a_][1] = *(const bf16x8*)(Ab_ + rowA + a_*2048 + slot1); } \
  _Pragma("unroll") for (int b_ = 0; b_ < 2; ++b_) { \
    bva_[b_][0] = *(const bf16x8*)(Bb_ + rowB + b_*2048 + slot0); \
    bva_[b_][1] = *(const bf16x8*)(Bb_ + rowB + b_*2048 + slot1); } \
  if (DOSTAGE) { STAGE_A2(BS, offA2_); STAGE_B01(BS, offB2_); } \
  __builtin_amdgcn_s_setprio(1); \
  _Pragma("unroll") for (int a_ = 0; a_ < 4; ++a_) { \
    _Pragma("unroll") for (int b_ = 0; b_ < 2; ++b_) { \
      acc[a_][b_] = __builtin_amdgcn_mfma_f32_16x16x32_bf16(av_[a_][0], bva_[b_][0], acc[a_][b_], 0, 0, 0); \
      acc[a_][b_] = __builtin_amdgcn_mfma_f32_16x16x32_bf16(av_[a_][1], bva_[b_][1], acc[a_][b_], 0, 0, 0); } } \
  __builtin_amdgcn_s_setprio(0); \
  _Pragma("unroll") for (int b_ = 0; b_ < 2; ++b_) { \
    bvb_[b_][0] = *(const bf16x8*)(Bb_ + rowB + 4096 + b_*2048 + slot0); \
    bvb_[b_][1] = *(const bf16x8*)(Bb_ + rowB + 4096 + b_*2048 + slot1); } \
  if (DOSTAGE) { STAGE_B23(BS, offB2_); } \
  __builtin_amdgcn_s_setprio(1); \
  _Pragma("unroll") for (int a_ = 0; a_ < 4; ++a_) { \
    _Pragma("unroll") for (int b_ = 0; b_ < 2; ++b_) { \
      acc[a_][b_+2] = __builtin_amdgcn_mfma_f32_16x16x32_bf16(av_[a_][0], bvb_[b_][0], acc[a_][b_+2], 0, 0, 0); \
      acc[a_][b_+2] = __builtin_amdgcn_mfma_f32_16x16x32_bf16(av_[a_][1], bvb_[b_][1], acc[a_][b_+2], 0, 0, 0); } } \
  __builtin_amdgcn_s_setprio(0); \
  if (DOBAR) { \
    asm volatile("s_waitcnt vmcnt(" VMCLIT ")" ::: "memory"); \
    __builtin_amdgcn_sched_barrier(0); \
    __builtin_amdgcn_s_barrier(); \
    __builtin_amdgcn_sched_barrier(0); } \
} while (0)

__global__ __launch_bounds__(512, 2) void conv_gemm(
    const __bf16* __restrict__ xt, const __bf16* __restrict__ wt,
    const float* __restrict__ bias, float* __restrict__ out) {
  // LDS: A bufs 3x16384 @0 ; B bufs 3x32768 @49152 ; total 147456 B (<=160K)
  __shared__ char lds[147456];
  int t = threadIdx.x;
  int mb = blockIdx.x;
  const char* xtc = (const char*)xt;
  const char* wtc = (const char*)wt;

  // ---- staging: linear LDS dest (t*16), PRE-SWIZZLED global source ----
  // issue covers 64 rows (8 lanes x 16 B per 128-B row); row&7 = (t>>3)&7.
  int arow = t >> 3;                                        // 0..63
  int kbsrc = ((t & 7) * 16) ^ ((arow & 7) << 4);           // swizzled slot in [0,128)
  int ldst = t * 16;
  uint32_t baseA[2];
#pragma unroll
  for (int i = 0; i < 2; ++i) {
    unsigned m = mb * BM + i * 64 + arow;
    unsigned nimg = m / HW;
    unsigned hw = m - nimg * HW;
    unsigned h = hw / WW;
    unsigned w = hw - h * WW;
    baseA[i] = ((nimg * HP + h) * HP + w) * (CI * 2) + kbsrc;
  }
  uint32_t baseB[4];
#pragma unroll
  for (int i = 0; i < 4; ++i)
    baseB[i] = (i * 64 + arow) * (KTOT * 2) + kbsrc;

  // ---- per-wave geometry: 8 waves = 2M x 4N, each 64x64 (4x4 fragments) ----
  int wid = t >> 6, lane = t & 63;
  int wm = (wid >> 2) * 64;        // 0,64
  int wn = (wid & 3) * 64;         // 0,64,128,192
  int lr = lane & 15, hi = lane >> 4;
  int swz = (lr & 7) << 4;
  int slot0 = (hi * 16) ^ swz;         // kk=0 slice, swizzled
  int slot1 = (64 + hi * 16) ^ swz;    // kk=1 slice
  int rowA = (wm + lr) * 128;          // + a*2048
  int rowB = (wn + lr) * 128;          // + b*2048

  f32x4 acc[4][4];
#pragma unroll
  for (int i = 0; i < 4; ++i)
#pragma unroll
    for (int j = 0; j < 4; ++j) acc[i][j] = (f32x4){0.f, 0.f, 0.f, 0.f};

  // ---- prologue: stage kt=0 -> buf0, kt=1 -> buf1 (12 issues) ----
  STAGE_A2(0, 0u);   STAGE_B01(0, 0u);   STAGE_B23(0, 0u);
  STAGE_A2(1, 128u); STAGE_B01(1, 128u); STAGE_B23(1, 128u);
  asm volatile("s_waitcnt vmcnt(6)" ::: "memory");   // kt0's 6 confirmed
  __builtin_amdgcn_sched_barrier(0);
  __builtin_amdgcn_s_barrier();
  __builtin_amdgcn_sched_barrier(0);

  // ---- main loop: 5 x 3 bodies (kt 0..14), buffers cycle 0,1,2 ----
  for (int kt = 0; kt < 15; kt += 3) {
    KBODY(kt + 0, 0, 2, 1, 1, "6");
    KBODY(kt + 1, 1, 0, 1, 1, "6");
    KBODY(kt + 2, 2, 1, 1, 1, "6");
  }
  // ---- tail: kt=15 stages kt17; kt=16 drains; kt=17 computes only ----
  KBODY(15, 0, 2, 1, 1, "6");
  KBODY(16, 1, 0, 0, 1, "0");
  KBODY(17, 2, 1, 0, 0, "0");

  // ---- epilogue: C/D layout col(=o)=lane&15, row(=m)=(lane>>4)*4+reg ----
  // 4 consecutive m are hw-contiguous (HW%4==0, quad never crosses an image)
  // and 16B-aligned -> float4 stores.
#pragma unroll
  for (int j = 0; j < 4; ++j) {
    int o = wn + j * 16 + lr;
    float bv = bias[o];
#pragma unroll
    for (int i = 0; i < 4; ++i) {
      unsigned m0 = mb * BM + wm + i * 16 + hi * 4;
      unsigned nimg = m0 / HW;
      unsigned hw = m0 - nimg * HW;
      f32x4 v = acc[i][j];
      v[0] += bv; v[1] += bv; v[2] += bv; v[3] += bv;
      *(f32x4*)(out + ((size_t)nimg * CO + o) * HW + hw) = v;
    }
  }
}

extern "C" void kernel_launch(void* const* d_in, const int* in_sizes, int n_in,
                              void* d_out, int out_size, void* d_ws, size_t ws_size,
                              hipStream_t stream) {
  const float* x    = (const float*)d_in[0];
  const float* wg   = (const float*)d_in[1];
  const float* bias = (const float*)d_in[2];
  float* out = (float*)d_out;

  __bf16* xt = (__bf16*)d_ws;
  __bf16* wt = (__bf16*)((char*)d_ws + XT_BYTES);

  halo_zero<<<(NB * 228 * 16 + 255) / 256, 256, 0, stream>>>(xt);
  xpose_kernel<<<NB * HH, 256, 0, stream>>>(x, xt);
  wxform_kernel<<<(CO * KTOT) / 256, 256, 0, stream>>>(wg, wt);
  conv_gemm<<<MTOT / BM, 512, 0, stream>>>(xt, wt, bias, out);
}